// Round 16
// baseline (83.927 us; speedup 1.0000x reference)
//
#include <hip/hip_runtime.h>

// LateralInhibitionAttention, MI355X.
// Conv3x3 of the rank-structured score matrix factorizes:
//   sum_{3x3} s[n+i][m+j] = (q[n-1]+q[n]+q[n+1]) . (k[m-1]+k[m]+k[m+1])
// so inhibited scores = [cq*q ; cs*qsum] . [k ; ksum]  (augmented 128-dim dot).
// R15: LN wave-per-row + attn qq-from-global trims (81.6 -> 80.8us).
// R16: gemm -> 2 waves/block, acc[4][4]/wave (16 MFMA per 8 ds_reads, 2x the
// MFMA:LDS ratio and ILP of R14's 4-wave acc[4][2]); m93/m97 precedent says
// 2.25 waves/SIMD suffices for this structure. Tile/grid/LDS unchanged.

using short8 = __attribute__((ext_vector_type(8))) short;
using short4v = __attribute__((ext_vector_type(4))) short;
using f32x4 = __attribute__((ext_vector_type(4))) float;

#define MFMA16(a, b, c) __builtin_amdgcn_mfma_f32_16x16x32_bf16((a), (b), (c), 0, 0, 0)

__device__ __forceinline__ float b2f(short s) {
    union { unsigned u; float f; } x;
    x.u = ((unsigned)(unsigned short)s) << 16;
    return x.f;
}
__device__ __forceinline__ short f2b(float f) {  // RNE f32->bf16
    unsigned u = __float_as_uint(f);
    unsigned r = (u + 0x7FFFu + ((u >> 16) & 1u)) >> 16;
    return (short)r;
}
__device__ __forceinline__ unsigned pk2(float lo, float hi) {  // packed bf16x2, 1 VALU op
    unsigned r;
    asm("v_cvt_pk_bf16_f32 %0, %1, %2" : "=v"(r) : "v"(lo), "v"(hi));
    return r;
}
// async global->LDS, 16B per lane; lds dest must be wave-uniform base (+lane*16 implicit)
__device__ __forceinline__ void gload_lds16(const short* g, short* l) {
    __builtin_amdgcn_global_load_lds(
        (const __attribute__((address_space(1))) void*)g,
        (__attribute__((address_space(3))) void*)l, 16, 0, 0);
}

// -------- prep: LN->bf16 wave-per-row (blocks 0..1023, 4 rows each) + W->bf16 (1024..2751) --------
__global__ __launch_bounds__(256) void prep_kernel(const float* __restrict__ x,
                                                   const float* __restrict__ g,
                                                   const float* __restrict__ bb,
                                                   const float* __restrict__ W,
                                                   short* __restrict__ xnb,
                                                   short* __restrict__ Wb) {
    int bid = blockIdx.x, t = threadIdx.x;
    if (bid >= 1024) {  // W f32 -> bf16 chunk
        int i = ((bid - 1024) * 256 + t) * 4;
        float4 v = *(const float4*)(W + i);
        short4v o;
        o[0] = f2b(v.x); o[1] = f2b(v.y); o[2] = f2b(v.z); o[3] = f2b(v.w);
        *(short4v*)(Wb + i) = o;
        return;
    }
    int w = t >> 6, l = t & 63;
    int row = bid * 4 + w;
    const float* xr = x + (size_t)row * 768;
    float4 a = *(const float4*)(xr + l * 4);
    float4 b = *(const float4*)(xr + 256 + l * 4);
    float4 c = *(const float4*)(xr + 512 + l * 4);
    float s = (a.x + a.y + a.z + a.w) + (b.x + b.y + b.z + b.w) + (c.x + c.y + c.z + c.w);
    float ss = (a.x * a.x + a.y * a.y + a.z * a.z + a.w * a.w) +
               (b.x * b.x + b.y * b.y + b.z * b.z + b.w * b.w) +
               (c.x * c.x + c.y * c.y + c.z * c.z + c.w * c.w);
#pragma unroll
    for (int o = 1; o < 64; o <<= 1) { s += __shfl_xor(s, o); ss += __shfl_xor(ss, o); }
    float mu = s * (1.0f / 768.0f);
    float var = ss * (1.0f / 768.0f) - mu * mu;
    float rs = rsqrtf(var + 1e-5f);
    float4 ga = *(const float4*)(g + l * 4);
    float4 gb = *(const float4*)(g + 256 + l * 4);
    float4 gc = *(const float4*)(g + 512 + l * 4);
    float4 ba = *(const float4*)(bb + l * 4);
    float4 bg = *(const float4*)(bb + 256 + l * 4);
    float4 bc = *(const float4*)(bb + 512 + l * 4);
    short* o = xnb + (size_t)row * 768;
    short4v o0, o1, o2;
    o0[0] = f2b((a.x - mu) * rs * ga.x + ba.x);
    o0[1] = f2b((a.y - mu) * rs * ga.y + ba.y);
    o0[2] = f2b((a.z - mu) * rs * ga.z + ba.z);
    o0[3] = f2b((a.w - mu) * rs * ga.w + ba.w);
    o1[0] = f2b((b.x - mu) * rs * gb.x + bg.x);
    o1[1] = f2b((b.y - mu) * rs * gb.y + bg.y);
    o1[2] = f2b((b.z - mu) * rs * gb.z + bg.z);
    o1[3] = f2b((b.w - mu) * rs * gb.w + bg.w);
    o2[0] = f2b((c.x - mu) * rs * gc.x + bc.x);
    o2[1] = f2b((c.y - mu) * rs * gc.y + bc.y);
    o2[2] = f2b((c.z - mu) * rs * gc.z + bc.z);
    o2[3] = f2b((c.w - mu) * rs * gc.w + bc.w);
    *(short4v*)(o + l * 4) = o0;
    *(short4v*)(o + 256 + l * 4) = o1;
    *(short4v*)(o + 512 + l * 4) = o2;
}

// ---------------- QKV GEMM: [4096,768]x[768,2304]^T, 64x128 tiles, 2 waves ----------------
// Grid (64,18) = 1152 blocks, 128 threads (2 waves), each wave 64 rows x 64 cols
// via acc[4][4] (16 MFMA per 8 ds_read_b128/K-step).
// blockIdx.y 0-5: Q (scaled cq*log2e), 6-11: K, 12-17: V -> VT via LDS transpose.
__global__ __launch_bounds__(128) void qkv_gemm(const short* __restrict__ A,
                                                const short* __restrict__ B,
                                                const float* __restrict__ bias,
                                                short* __restrict__ Qb,
                                                short* __restrict__ Kb,
                                                short* __restrict__ VT) {
    __shared__ char smem[12288];
    short* As = (short*)smem;            // [64][32] bf16
    short* Bs = (short*)(smem + 4096);   // [128][32] bf16
    int t = threadIdx.x, w = t >> 6, l = t & 63, lr = l & 15, lg = l >> 4;
    int row0 = blockIdx.x * 64;
    int col0 = blockIdx.y * 128;
    // staging: call c covers rows c*32 + (t>>2), 8-col group (t&3); wave-uniform dest
    const short* agp = A + (size_t)(row0 + (t >> 2)) * 768 + (t & 3) * 8;
    const short* bgp = B + (size_t)(col0 + (t >> 2)) * 768 + (t & 3) * 8;
    short* asl = As + (w * 64) * 8;
    short* bsl = Bs + (w * 64) * 8;

    f32x4 acc[4][4];
#pragma unroll
    for (int m = 0; m < 4; ++m)
#pragma unroll
        for (int n = 0; n < 4; ++n) acc[m][n] = (f32x4){0.f, 0.f, 0.f, 0.f};

    for (int k0 = 0; k0 < 768; k0 += 32) {
        gload_lds16(agp + k0, asl);
        gload_lds16(agp + (size_t)32 * 768 + k0, asl + 1024);
        gload_lds16(bgp + k0, bsl);
        gload_lds16(bgp + (size_t)32 * 768 + k0, bsl + 1024);
        gload_lds16(bgp + (size_t)64 * 768 + k0, bsl + 2048);
        gload_lds16(bgp + (size_t)96 * 768 + k0, bsl + 3072);
        __syncthreads();
        short8 af[4], bf[4];
#pragma unroll
        for (int m = 0; m < 4; ++m)
            af[m] = *(short8*)&As[(m * 16 + lr) * 32 + lg * 8];
#pragma unroll
        for (int n = 0; n < 4; ++n)
            bf[n] = *(short8*)&Bs[(w * 64 + n * 16 + lr) * 32 + lg * 8];
#pragma unroll
        for (int m = 0; m < 4; ++m)
#pragma unroll
            for (int n = 0; n < 4; ++n)
                acc[m][n] = MFMA16(af[m], bf[n], acc[m][n]);
        __syncthreads();
    }

    int sec = blockIdx.y / 6;  // uniform per block
    if (sec < 2) {
        short* dst = sec ? Kb : Qb;
        // Q pre-scale: 1.2 * D^-0.5 * log2(e)  -> scores arrive in log2 space.
        const float scl = sec ? 1.0f : (1.2f * 0.125f * 1.44269504088896f);
#pragma unroll
        for (int n = 0; n < 4; ++n) {
            int j = col0 + w * 64 + n * 16 + lr;
            float bs = bias[j];
            int jj = j - sec * 768;
            int h = jj >> 6, d = jj & 63;
#pragma unroll
            for (int m = 0; m < 4; ++m)
#pragma unroll
                for (int i = 0; i < 4; ++i) {
                    int row = row0 + m * 16 + lg * 4 + i;
                    int b = row >> 10, n_ = row & 1023;
                    dst[(size_t)(((b * 12 + h) << 10) | n_) * 64 + d] =
                        f2b(scl * (acc[m][n][i] + bs));
                }
        }
    } else {
        // V: transpose 64x128 tile -> VT[d][n], two 64-col passes through LDS.
        short* tr = (short*)smem;  // [64 cols][72]
        int b = row0 >> 10, nin = row0 & 1023;
        int jj0 = col0 - 1536;
        for (int p = 0; p < 2; ++p) {
            __syncthreads();
            if (w == p) {   // wave p owns cols p*64..p*64+63
#pragma unroll
                for (int n = 0; n < 4; ++n) {
                    int jl = n * 16 + lr;
                    float bs = bias[col0 + p * 64 + jl];
#pragma unroll
                    for (int m = 0; m < 4; ++m) {
                        int nl = m * 16 + lg * 4;
                        short4v o;
#pragma unroll
                        for (int i = 0; i < 4; ++i) o[i] = f2b(acc[m][n][i] + bs);
                        *(short4v*)&tr[jl * 72 + nl] = o;
                    }
                }
            }
            __syncthreads();
            int jl2 = t >> 1, half = t & 1;
            int j = jj0 + p * 64 + jl2;
            int h = j >> 6, d = j & 63;
            short* vtb = VT + (size_t)(b * 12 + h) * 65536 + d * 1024 + nin + half * 32;
#pragma unroll
            for (int u = 0; u < 4; ++u)
                *(short8*)(vtb + u * 8) = *(short8*)&tr[jl2 * 72 + half * 32 + u * 8];
        }
    }
}

// ---------------- KK = k[n-1]+k[n]+k[n+1] (zero-padded) ----------------
__global__ __launch_bounds__(256) void kk_kernel(const short* __restrict__ Kb,
                                                 short* __restrict__ KK) {
    int bh = blockIdx.y;
    int t = threadIdx.x;
    int n = blockIdx.x * 32 + (t >> 3), dc = (t & 7) * 8;
    const short* kp = Kb + (size_t)bh * 65536;
    float s[8];
    short8 c = *(const short8*)(kp + n * 64 + dc);
#pragma unroll
    for (int e = 0; e < 8; ++e) s[e] = b2f(c[e]);
    if (n > 0) {
        short8 m = *(const short8*)(kp + (n - 1) * 64 + dc);
#pragma unroll
        for (int e = 0; e < 8; ++e) s[e] += b2f(m[e]);
    }
    if (n < 1023) {
        short8 p = *(const short8*)(kp + (n + 1) * 64 + dc);
#pragma unroll
        for (int e = 0; e < 8; ++e) s[e] += b2f(p[e]);
    }
    short8 o;
#pragma unroll
    for (int e = 0; e < 8; ++e) o[e] = f2b(s[e]);
    *(short8*)(KK + (size_t)bh * 65536 + n * 64 + dc) = o;
}

// ---------------- flash attention: online softmax (log2-space), no S buffer ----------------
// Block: 64 q-rows (4 waves x 16), loop over 16 KV-tiles of 64 keys.
// Swapped QK^T: mfma(A=K, B=Q) -> D[key][q], q = lane&15 (lane-local stats).
// bfr[2..3] (-1/6 Q-neighbor sums) computed per-lane from global (no qq LDS).
// K/KK/VT tiles staged via global_load_lds with XOR-16B-unit swizzle.
// PV: mfma(A=VT, B=P) -> O^T[d][q]; normalize once at the end.  (R12-proven form.)
__global__ __launch_bounds__(256, 3) void attn_kernel(const short* __restrict__ Qb,
                                                      const short* __restrict__ Kb,
                                                      const short* __restrict__ KK,
                                                      const short* __restrict__ VT,
                                                      float* __restrict__ out) {
    __shared__ short Kt[4096];    // [64 key][64 d], 16B-unit col ^ (row&7)
    __shared__ short KKt[4096];
    __shared__ short VTt[4096];   // [64 d][64 key], same swizzle
    __shared__ short Plds[4][16][72];  // per-wave P: [q][key], padded rows
    int dd = blockIdx.x;
    int xcd = dd & 7, rr = dd >> 3;
    int r0 = (rr & 15) * 64;
    int bh = (rr >> 4) * 8 + xcd;
    int t = threadIdx.x, w = t >> 6, l = t & 63, lr = l & 15, lg = l >> 4;
    const short* qp = Qb + (size_t)bh * 65536;
    const short* kp = Kb + (size_t)bh * 65536;
    const short* kk = KK + (size_t)bh * 65536;
    const short* vt = VT + (size_t)bh * 65536;

    // Q B-operand frags for this wave's 16 q-rows (K=128 augmented).
    // bfr[2..3] = -(1/6)*(Q[n-1]+Q[n]+Q[n+1]) per-lane from global (zero-padded).
    int nq = r0 + w * 16 + lr;
    const short* qrow = qp + (size_t)nq * 64 + lg * 8;
    short8 bfr[4];
    bfr[0] = *(const short8*)(qrow);
    bfr[1] = *(const short8*)(qrow + 32);
    {
        float s0[8], s1[8];
#pragma unroll
        for (int e = 0; e < 8; ++e) { s0[e] = b2f(bfr[0][e]); s1[e] = b2f(bfr[1][e]); }
        if (nq > 0) {
            short8 m0 = *(const short8*)(qrow - 64);
            short8 m1 = *(const short8*)(qrow - 64 + 32);
#pragma unroll
            for (int e = 0; e < 8; ++e) { s0[e] += b2f(m0[e]); s1[e] += b2f(m1[e]); }
        }
        if (nq < 1023) {
            short8 p0 = *(const short8*)(qrow + 64);
            short8 p1 = *(const short8*)(qrow + 64 + 32);
#pragma unroll
            for (int e = 0; e < 8; ++e) { s0[e] += b2f(p0[e]); s1[e] += b2f(p1[e]); }
        }
#pragma unroll
        for (int e = 0; e < 8; ++e) {
            bfr[2][e] = f2b(-(1.0f / 6.0f) * s0[e]);
            bfr[3][e] = f2b(-(1.0f / 6.0f) * s1[e]);
        }
    }

    // Staging: unit u covers rows (u>>3), 16B col (u&7); source pre-swizzled.
    int srow = t >> 3, sc = ((t & 7) ^ (srow & 7)) * 8;
    const short* gk = kp + srow * 64 + sc;       // +2048 shorts for second half
    const short* gkk = kk + srow * 64 + sc;
    const short* gv = vt + srow * 1024 + sc;     // +32768 for second half
    short* dk0 = Kt + w * 512;   short* dk1 = Kt + 2048 + w * 512;
    short* dkk0 = KKt + w * 512; short* dkk1 = KKt + 2048 + w * 512;
    short* dv0 = VTt + w * 512;  short* dv1 = VTt + 2048 + w * 512;
    short* pw = &Plds[w][0][0];
    short* pwr = pw + lr * 72;

    f32x4 O[4];
#pragma unroll
    for (int m = 0; m < 4; ++m) O[m] = (f32x4){0.f, 0.f, 0.f, 0.f};
    float m_run = -1e30f, l_run = 0.f;

    for (int tt = 0; tt < 16; ++tt) {
        int ko = tt * 64;  // key offset
        gload_lds16(gk + ko * 64, dk0);
        gload_lds16(gk + ko * 64 + 2048, dk1);
        gload_lds16(gkk + ko * 64, dkk0);
        gload_lds16(gkk + ko * 64 + 2048, dkk1);
        gload_lds16(gv + ko, dv0);
        gload_lds16(gv + ko + 32768, dv1);
        __syncthreads();  // drains vmcnt: staging complete

        // QK^T: D[key][q] (log2-space scores), 64 keys x 16 q per wave.
        f32x4 sacc[4];
        __builtin_amdgcn_s_setprio(1);
#pragma unroll
        for (int ct = 0; ct < 4; ++ct) {
            int r = ct * 16 + lr, rs = r * 64, rx = r & 7;
            short8 a0 = *(short8*)&Kt[rs + (((0 + lg) ^ rx) << 3)];
            short8 a1 = *(short8*)&Kt[rs + (((4 + lg) ^ rx) << 3)];
            short8 a2 = *(short8*)&KKt[rs + (((0 + lg) ^ rx) << 3)];
            short8 a3 = *(short8*)&KKt[rs + (((4 + lg) ^ rx) << 3)];
            f32x4 s_ = (f32x4){0.f, 0.f, 0.f, 0.f};
            s_ = MFMA16(a0, bfr[0], s_);
            s_ = MFMA16(a1, bfr[1], s_);
            s_ = MFMA16(a2, bfr[2], s_);
            s_ = MFMA16(a3, bfr[3], s_);
            sacc[ct] = s_;
        }
        __builtin_amdgcn_s_setprio(0);
        // Online softmax in log2 space (q = lr lane-local; keys split across lg).
        float mt_ = fmaxf(fmaxf(fmaxf(sacc[0][0], sacc[0][1]), fmaxf(sacc[0][2], sacc[0][3])),
                          fmaxf(fmaxf(sacc[1][0], sacc[1][1]), fmaxf(sacc[1][2], sacc[1][3])));
        float mt2 = fmaxf(fmaxf(fmaxf(sacc[2][0], sacc[2][1]), fmaxf(sacc[2][2], sacc[2][3])),
                          fmaxf(fmaxf(sacc[3][0], sacc[3][1]), fmaxf(sacc[3][2], sacc[3][3])));
        mt_ = fmaxf(mt_, mt2);
        mt_ = fmaxf(mt_, __shfl_xor(mt_, 16));
        mt_ = fmaxf(mt_, __shfl_xor(mt_, 32));
        // Defer-max: only rescale when the tile max pushes past m_run + 8.
        if (__any(mt_ > m_run + 8.0f)) {
            float mnew = fmaxf(m_run, mt_);
            float sc_ = __builtin_amdgcn_exp2f(m_run - mnew);
            m_run = mnew;
            l_run *= sc_;
#pragma unroll
            for (int m = 0; m < 4; ++m)
#pragma unroll
                for (int i = 0; i < 4; ++i) O[m][i] *= sc_;
        }
        float ps = 0.f;
#pragma unroll
        for (int ct = 0; ct < 4; ++ct) {
            float p0 = __builtin_amdgcn_exp2f(sacc[ct][0] - m_run);
            float p1 = __builtin_amdgcn_exp2f(sacc[ct][1] - m_run);
            float p2 = __builtin_amdgcn_exp2f(sacc[ct][2] - m_run);
            float p3 = __builtin_amdgcn_exp2f(sacc[ct][3] - m_run);
            ps += (p0 + p1) + (p2 + p3);
            uint2 wv;
            wv.x = pk2(p0, p1);
            wv.y = pk2(p2, p3);
            *(uint2*)&pwr[ct * 16 + lg * 4] = wv;
        }
        l_run += ps;
        // PV: O^T[d][q] += VT-tile . P-tile
        short8 pb0 = *(short8*)&pwr[lg * 8];
        short8 pb1 = *(short8*)&pwr[32 + lg * 8];
        __builtin_amdgcn_s_setprio(1);
#pragma unroll
        for (int m = 0; m < 4; ++m) {
            int r = m * 16 + lr, rs = r * 64, rx = r & 7;
            short8 v0 = *(short8*)&VTt[rs + (((0 + lg) ^ rx) << 3)];
            short8 v1 = *(short8*)&VTt[rs + (((4 + lg) ^ rx) << 3)];
            O[m] = MFMA16(v0, pb0, O[m]);
            O[m] = MFMA16(v1, pb1, O[m]);
        }
        __builtin_amdgcn_s_setprio(0);
        __syncthreads();  // all waves done reading tile before next stage
    }

    l_run += __shfl_xor(l_run, 16);
    l_run += __shfl_xor(l_run, 32);
    float inv = 1.f / l_run;
    int b = bh / 12, h = bh - b * 12;
    int q = r0 + w * 16 + lr;
    float* ob = out + (size_t)(b * 1024 + q) * 768 + h * 64;
#pragma unroll
    for (int m = 0; m < 4; ++m) {
        float4 o4;
        o4.x = O[m][0] * inv; o4.y = O[m][1] * inv;
        o4.z = O[m][2] * inv; o4.w = O[m][3] * inv;
        *(float4*)(ob + m * 16 + lg * 4) = o4;
    }
}

extern "C" void kernel_launch(void* const* d_in, const int* in_sizes, int n_in,
                              void* d_out, int out_size, void* d_ws, size_t ws_size,
                              hipStream_t stream) {
    const float* x  = (const float*)d_in[0];
    const float* W  = (const float*)d_in[1];
    const float* qb = (const float*)d_in[2];
    const float* lg = (const float*)d_in[3];
    const float* lb = (const float*)d_in[4];
    float* out = (float*)d_out;
    char* ws = (char*)d_ws;
    // Workspace layout (peak 28,704,768 bytes):
    short* xnb = (short*)(ws + 0);         // [4096][768] bf16 (dead after gemm)
    short* Wb  = (short*)(ws + 6291456);   // [2304][768] bf16
    short* Qb  = (short*)(ws + 9830400);   // [48][1024][64] bf16, pre-scaled by cq*log2e
    short* Kb  = (short*)(ws + 16121856);  // [48][1024][64] bf16
    short* VT  = (short*)(ws + 22413312);  // [48][64][1024] bf16
    short* KK  = (short*)(ws + 0);         // [48][1024][64] bf16, overlays dead xnb

    hipLaunchKernelGGL(prep_kernel, dim3(2752), dim3(256), 0, stream, x, lg, lb, W, xnb, Wb);
    hipLaunchKernelGGL(qkv_gemm, dim3(64, 18), dim3(128), 0, stream, xnb, Wb, qb, Qb, Kb, VT);
    hipLaunchKernelGGL(kk_kernel, dim3(32, 48), dim3(256), 0, stream, Kb, KK);
    hipLaunchKernelGGL(attn_kernel, dim3(768), dim3(256), 0, stream, Qb, Kb, KK, VT, out);
}

// Round 17
// 80.925 us; speedup vs baseline: 1.0371x; 1.0371x over previous
//
#include <hip/hip_runtime.h>

// LateralInhibitionAttention, MI355X.
// Conv3x3 of the rank-structured score matrix factorizes:
//   sum_{3x3} s[n+i][m+j] = (q[n-1]+q[n]+q[n+1]) . (k[m-1]+k[m]+k[m+1])
// so inhibited scores = [cq*q ; cs*qsum] . [k ; ksum]  (augmented 128-dim dot).
// R16 post-mortem: 2-wave acc[4][4] gemm regressed (83.9us) -> reverted to the
// R14/R15-proven 4-wave 64x128 gemm. This is the measured-best configuration
// (R15: 80.8us): prep(LN wave-per-row + W cast) -> gemm -> kk -> flash attn.

using short8 = __attribute__((ext_vector_type(8))) short;
using short4v = __attribute__((ext_vector_type(4))) short;
using f32x4 = __attribute__((ext_vector_type(4))) float;

#define MFMA16(a, b, c) __builtin_amdgcn_mfma_f32_16x16x32_bf16((a), (b), (c), 0, 0, 0)

__device__ __forceinline__ float b2f(short s) {
    union { unsigned u; float f; } x;
    x.u = ((unsigned)(unsigned short)s) << 16;
    return x.f;
}
__device__ __forceinline__ short f2b(float f) {  // RNE f32->bf16
    unsigned u = __float_as_uint(f);
    unsigned r = (u + 0x7FFFu + ((u >> 16) & 1u)) >> 16;
    return (short)r;
}
__device__ __forceinline__ unsigned pk2(float lo, float hi) {  // packed bf16x2, 1 VALU op
    unsigned r;
    asm("v_cvt_pk_bf16_f32 %0, %1, %2" : "=v"(r) : "v"(lo), "v"(hi));
    return r;
}
// async global->LDS, 16B per lane; lds dest must be wave-uniform base (+lane*16 implicit)
__device__ __forceinline__ void gload_lds16(const short* g, short* l) {
    __builtin_amdgcn_global_load_lds(
        (const __attribute__((address_space(1))) void*)g,
        (__attribute__((address_space(3))) void*)l, 16, 0, 0);
}

// -------- prep: LN->bf16 wave-per-row (blocks 0..1023, 4 rows each) + W->bf16 (1024..2751) --------
__global__ __launch_bounds__(256) void prep_kernel(const float* __restrict__ x,
                                                   const float* __restrict__ g,
                                                   const float* __restrict__ bb,
                                                   const float* __restrict__ W,
                                                   short* __restrict__ xnb,
                                                   short* __restrict__ Wb) {
    int bid = blockIdx.x, t = threadIdx.x;
    if (bid >= 1024) {  // W f32 -> bf16 chunk
        int i = ((bid - 1024) * 256 + t) * 4;
        float4 v = *(const float4*)(W + i);
        short4v o;
        o[0] = f2b(v.x); o[1] = f2b(v.y); o[2] = f2b(v.z); o[3] = f2b(v.w);
        *(short4v*)(Wb + i) = o;
        return;
    }
    int w = t >> 6, l = t & 63;
    int row = bid * 4 + w;
    const float* xr = x + (size_t)row * 768;
    float4 a = *(const float4*)(xr + l * 4);
    float4 b = *(const float4*)(xr + 256 + l * 4);
    float4 c = *(const float4*)(xr + 512 + l * 4);
    float s = (a.x + a.y + a.z + a.w) + (b.x + b.y + b.z + b.w) + (c.x + c.y + c.z + c.w);
    float ss = (a.x * a.x + a.y * a.y + a.z * a.z + a.w * a.w) +
               (b.x * b.x + b.y * b.y + b.z * b.z + b.w * b.w) +
               (c.x * c.x + c.y * c.y + c.z * c.z + c.w * c.w);
#pragma unroll
    for (int o = 1; o < 64; o <<= 1) { s += __shfl_xor(s, o); ss += __shfl_xor(ss, o); }
    float mu = s * (1.0f / 768.0f);
    float var = ss * (1.0f / 768.0f) - mu * mu;
    float rs = rsqrtf(var + 1e-5f);
    float4 ga = *(const float4*)(g + l * 4);
    float4 gb = *(const float4*)(g + 256 + l * 4);
    float4 gc = *(const float4*)(g + 512 + l * 4);
    float4 ba = *(const float4*)(bb + l * 4);
    float4 bg = *(const float4*)(bb + 256 + l * 4);
    float4 bc = *(const float4*)(bb + 512 + l * 4);
    short* o = xnb + (size_t)row * 768;
    short4v o0, o1, o2;
    o0[0] = f2b((a.x - mu) * rs * ga.x + ba.x);
    o0[1] = f2b((a.y - mu) * rs * ga.y + ba.y);
    o0[2] = f2b((a.z - mu) * rs * ga.z + ba.z);
    o0[3] = f2b((a.w - mu) * rs * ga.w + ba.w);
    o1[0] = f2b((b.x - mu) * rs * gb.x + bg.x);
    o1[1] = f2b((b.y - mu) * rs * gb.y + bg.y);
    o1[2] = f2b((b.z - mu) * rs * gb.z + bg.z);
    o1[3] = f2b((b.w - mu) * rs * gb.w + bg.w);
    o2[0] = f2b((c.x - mu) * rs * gc.x + bc.x);
    o2[1] = f2b((c.y - mu) * rs * gc.y + bc.y);
    o2[2] = f2b((c.z - mu) * rs * gc.z + bc.z);
    o2[3] = f2b((c.w - mu) * rs * gc.w + bc.w);
    *(short4v*)(o + l * 4) = o0;
    *(short4v*)(o + 256 + l * 4) = o1;
    *(short4v*)(o + 512 + l * 4) = o2;
}

// ---------------- QKV GEMM: [4096,768]x[768,2304]^T, 64x128 tiles (R14-proven) ----------------
__global__ __launch_bounds__(256) void qkv_gemm(const short* __restrict__ A,
                                                const short* __restrict__ B,
                                                const float* __restrict__ bias,
                                                short* __restrict__ Qb,
                                                short* __restrict__ Kb,
                                                short* __restrict__ VT) {
    __shared__ char smem[12288];
    short* As = (short*)smem;            // [64][32] bf16
    short* Bs = (short*)(smem + 4096);   // [128][32] bf16
    int t = threadIdx.x, w = t >> 6, l = t & 63, lr = l & 15, lg = l >> 4;
    int row0 = blockIdx.x * 64;
    int col0 = blockIdx.y * 128;
    const short* agp  = A + (size_t)(row0 + (t >> 2)) * 768 + (t & 3) * 8;
    const short* bgp0 = B + (size_t)(col0 + (t >> 2)) * 768 + (t & 3) * 8;
    const short* bgp1 = bgp0 + (size_t)64 * 768;
    short* asl  = As + (w * 64) * 8;
    short* bsl0 = Bs + (w * 64) * 8;
    short* bsl1 = Bs + (256 + w * 64) * 8;

    f32x4 acc[4][2];
#pragma unroll
    for (int m = 0; m < 4; ++m)
#pragma unroll
        for (int n = 0; n < 2; ++n) acc[m][n] = (f32x4){0.f, 0.f, 0.f, 0.f};

    for (int k0 = 0; k0 < 768; k0 += 32) {
        gload_lds16(agp + k0, asl);
        gload_lds16(bgp0 + k0, bsl0);
        gload_lds16(bgp1 + k0, bsl1);
        __syncthreads();
        short8 af[4], bf[2];
#pragma unroll
        for (int m = 0; m < 4; ++m)
            af[m] = *(short8*)&As[(m * 16 + lr) * 32 + lg * 8];
#pragma unroll
        for (int n = 0; n < 2; ++n)
            bf[n] = *(short8*)&Bs[(w * 32 + n * 16 + lr) * 32 + lg * 8];
#pragma unroll
        for (int m = 0; m < 4; ++m)
#pragma unroll
            for (int n = 0; n < 2; ++n)
                acc[m][n] = MFMA16(af[m], bf[n], acc[m][n]);
        __syncthreads();
    }

    int sec = blockIdx.y / 6;  // uniform per block
    if (sec < 2) {
        short* dst = sec ? Kb : Qb;
        // Q pre-scale: 1.2 * D^-0.5 * log2(e)  -> scores arrive in log2 space.
        const float scl = sec ? 1.0f : (1.2f * 0.125f * 1.44269504088896f);
#pragma unroll
        for (int n = 0; n < 2; ++n) {
            int j = col0 + w * 32 + n * 16 + lr;
            float bs = bias[j];
            int jj = j - sec * 768;
            int h = jj >> 6, d = jj & 63;
#pragma unroll
            for (int m = 0; m < 4; ++m)
#pragma unroll
                for (int i = 0; i < 4; ++i) {
                    int row = row0 + m * 16 + lg * 4 + i;
                    int b = row >> 10, n_ = row & 1023;
                    dst[(size_t)(((b * 12 + h) << 10) | n_) * 64 + d] =
                        f2b(scl * (acc[m][n][i] + bs));
                }
        }
    } else {
        // V: transpose 64x128 tile -> VT[d][n], two 64-col passes through LDS.
        short* tr = (short*)smem;  // [64 cols][72]
        int b = row0 >> 10, nin = row0 & 1023;
        int jj0 = col0 - 1536;
        for (int p = 0; p < 2; ++p) {
            __syncthreads();
            if ((w >> 1) == p) {   // waves 2p,2p+1 own cols p*64..p*64+63
#pragma unroll
                for (int n = 0; n < 2; ++n) {
                    int jl = (w & 1) * 32 + n * 16 + lr;
                    float bs = bias[col0 + p * 64 + jl];
#pragma unroll
                    for (int m = 0; m < 4; ++m) {
                        int nl = m * 16 + lg * 4;
                        short4v o;
#pragma unroll
                        for (int i = 0; i < 4; ++i) o[i] = f2b(acc[m][n][i] + bs);
                        *(short4v*)&tr[jl * 72 + nl] = o;
                    }
                }
            }
            __syncthreads();
            int jl2 = t >> 2, qd = t & 3;
            int j = jj0 + p * 64 + jl2;
            int h = j >> 6, d = j & 63;
            short* vtb = VT + (size_t)(b * 12 + h) * 65536 + d * 1024 + nin + qd * 16;
            *(short8*)(vtb)     = *(short8*)&tr[jl2 * 72 + qd * 16];
            *(short8*)(vtb + 8) = *(short8*)&tr[jl2 * 72 + qd * 16 + 8];
        }
    }
}

// ---------------- KK = k[n-1]+k[n]+k[n+1] (zero-padded) ----------------
__global__ __launch_bounds__(256) void kk_kernel(const short* __restrict__ Kb,
                                                 short* __restrict__ KK) {
    int bh = blockIdx.y;
    int t = threadIdx.x;
    int n = blockIdx.x * 32 + (t >> 3), dc = (t & 7) * 8;
    const short* kp = Kb + (size_t)bh * 65536;
    float s[8];
    short8 c = *(const short8*)(kp + n * 64 + dc);
#pragma unroll
    for (int e = 0; e < 8; ++e) s[e] = b2f(c[e]);
    if (n > 0) {
        short8 m = *(const short8*)(kp + (n - 1) * 64 + dc);
#pragma unroll
        for (int e = 0; e < 8; ++e) s[e] += b2f(m[e]);
    }
    if (n < 1023) {
        short8 p = *(const short8*)(kp + (n + 1) * 64 + dc);
#pragma unroll
        for (int e = 0; e < 8; ++e) s[e] += b2f(p[e]);
    }
    short8 o;
#pragma unroll
    for (int e = 0; e < 8; ++e) o[e] = f2b(s[e]);
    *(short8*)(KK + (size_t)bh * 65536 + n * 64 + dc) = o;
}

// ---------------- flash attention: online softmax (log2-space), no S buffer ----------------
// Block: 64 q-rows (4 waves x 16), loop over 16 KV-tiles of 64 keys.
// Swapped QK^T: mfma(A=K, B=Q) -> D[key][q], q = lane&15 (lane-local stats).
// bfr[2..3] (-1/6 Q-neighbor sums) computed per-lane from global (no qq LDS).
// K/KK/VT tiles staged via global_load_lds with XOR-16B-unit swizzle.
// PV: mfma(A=VT, B=P) -> O^T[d][q]; normalize once at the end.
__global__ __launch_bounds__(256, 3) void attn_kernel(const short* __restrict__ Qb,
                                                      const short* __restrict__ Kb,
                                                      const short* __restrict__ KK,
                                                      const short* __restrict__ VT,
                                                      float* __restrict__ out) {
    __shared__ short Kt[4096];    // [64 key][64 d], 16B-unit col ^ (row&7)
    __shared__ short KKt[4096];
    __shared__ short VTt[4096];   // [64 d][64 key], same swizzle
    __shared__ short Plds[4][16][72];  // per-wave P: [q][key], padded rows
    int dd = blockIdx.x;
    int xcd = dd & 7, rr = dd >> 3;
    int r0 = (rr & 15) * 64;
    int bh = (rr >> 4) * 8 + xcd;
    int t = threadIdx.x, w = t >> 6, l = t & 63, lr = l & 15, lg = l >> 4;
    const short* qp = Qb + (size_t)bh * 65536;
    const short* kp = Kb + (size_t)bh * 65536;
    const short* kk = KK + (size_t)bh * 65536;
    const short* vt = VT + (size_t)bh * 65536;

    // Q B-operand frags for this wave's 16 q-rows (K=128 augmented).
    // bfr[2..3] = -(1/6)*(Q[n-1]+Q[n]+Q[n+1]) per-lane from global (zero-padded).
    int nq = r0 + w * 16 + lr;
    const short* qrow = qp + (size_t)nq * 64 + lg * 8;
    short8 bfr[4];
    bfr[0] = *(const short8*)(qrow);
    bfr[1] = *(const short8*)(qrow + 32);
    {
        float s0[8], s1[8];
#pragma unroll
        for (int e = 0; e < 8; ++e) { s0[e] = b2f(bfr[0][e]); s1[e] = b2f(bfr[1][e]); }
        if (nq > 0) {
            short8 m0 = *(const short8*)(qrow - 64);
            short8 m1 = *(const short8*)(qrow - 64 + 32);
#pragma unroll
            for (int e = 0; e < 8; ++e) { s0[e] += b2f(m0[e]); s1[e] += b2f(m1[e]); }
        }
        if (nq < 1023) {
            short8 p0 = *(const short8*)(qrow + 64);
            short8 p1 = *(const short8*)(qrow + 64 + 32);
#pragma unroll
            for (int e = 0; e < 8; ++e) { s0[e] += b2f(p0[e]); s1[e] += b2f(p1[e]); }
        }
#pragma unroll
        for (int e = 0; e < 8; ++e) {
            bfr[2][e] = f2b(-(1.0f / 6.0f) * s0[e]);
            bfr[3][e] = f2b(-(1.0f / 6.0f) * s1[e]);
        }
    }

    // Staging: unit u covers rows (u>>3), 16B col (u&7); source pre-swizzled.
    int srow = t >> 3, sc = ((t & 7) ^ (srow & 7)) * 8;
    const short* gk = kp + srow * 64 + sc;       // +2048 shorts for second half
    const short* gkk = kk + srow * 64 + sc;
    const short* gv = vt + srow * 1024 + sc;     // +32768 for second half
    short* dk0 = Kt + w * 512;   short* dk1 = Kt + 2048 + w * 512;
    short* dkk0 = KKt + w * 512; short* dkk1 = KKt + 2048 + w * 512;
    short* dv0 = VTt + w * 512;  short* dv1 = VTt + 2048 + w * 512;
    short* pw = &Plds[w][0][0];
    short* pwr = pw + lr * 72;

    f32x4 O[4];
#pragma unroll
    for (int m = 0; m < 4; ++m) O[m] = (f32x4){0.f, 0.f, 0.f, 0.f};
    float m_run = -1e30f, l_run = 0.f;

    for (int tt = 0; tt < 16; ++tt) {
        int ko = tt * 64;  // key offset
        gload_lds16(gk + ko * 64, dk0);
        gload_lds16(gk + ko * 64 + 2048, dk1);
        gload_lds16(gkk + ko * 64, dkk0);
        gload_lds16(gkk + ko * 64 + 2048, dkk1);
        gload_lds16(gv + ko, dv0);
        gload_lds16(gv + ko + 32768, dv1);
        __syncthreads();  // drains vmcnt: staging complete

        // QK^T: D[key][q] (log2-space scores), 64 keys x 16 q per wave.
        f32x4 sacc[4];
        __builtin_amdgcn_s_setprio(1);
#pragma unroll
        for (int ct = 0; ct < 4; ++ct) {
            int r = ct * 16 + lr, rs = r * 64, rx = r & 7;
            short8 a0 = *(short8*)&Kt[rs + (((0 + lg) ^ rx) << 3)];
            short8 a1 = *(short8*)&Kt[rs + (((4 + lg) ^ rx) << 3)];
            short8 a2 = *(short8*)&KKt[rs + (((0 + lg) ^ rx) << 3)];
            short8 a3 = *(short8*)&KKt[rs + (((4 + lg) ^ rx) << 3)];
            f32x4 s_ = (f32x4){0.f, 0.f, 0.f, 0.f};
            s_ = MFMA16(a0, bfr[0], s_);
            s_ = MFMA16(a1, bfr[1], s_);
            s_ = MFMA16(a2, bfr[2], s_);
            s_ = MFMA16(a3, bfr[3], s_);
            sacc[ct] = s_;
        }
        __builtin_amdgcn_s_setprio(0);
        // Online softmax in log2 space (q = lr lane-local; keys split across lg).
        float mt_ = fmaxf(fmaxf(fmaxf(sacc[0][0], sacc[0][1]), fmaxf(sacc[0][2], sacc[0][3])),
                          fmaxf(fmaxf(sacc[1][0], sacc[1][1]), fmaxf(sacc[1][2], sacc[1][3])));
        float mt2 = fmaxf(fmaxf(fmaxf(sacc[2][0], sacc[2][1]), fmaxf(sacc[2][2], sacc[2][3])),
                          fmaxf(fmaxf(sacc[3][0], sacc[3][1]), fmaxf(sacc[3][2], sacc[3][3])));
        mt_ = fmaxf(mt_, mt2);
        mt_ = fmaxf(mt_, __shfl_xor(mt_, 16));
        mt_ = fmaxf(mt_, __shfl_xor(mt_, 32));
        // Defer-max: only rescale when the tile max pushes past m_run + 8.
        if (__any(mt_ > m_run + 8.0f)) {
            float mnew = fmaxf(m_run, mt_);
            float sc_ = __builtin_amdgcn_exp2f(m_run - mnew);
            m_run = mnew;
            l_run *= sc_;
#pragma unroll
            for (int m = 0; m < 4; ++m)
#pragma unroll
                for (int i = 0; i < 4; ++i) O[m][i] *= sc_;
        }
        float ps = 0.f;
#pragma unroll
        for (int ct = 0; ct < 4; ++ct) {
            float p0 = __builtin_amdgcn_exp2f(sacc[ct][0] - m_run);
            float p1 = __builtin_amdgcn_exp2f(sacc[ct][1] - m_run);
            float p2 = __builtin_amdgcn_exp2f(sacc[ct][2] - m_run);
            float p3 = __builtin_amdgcn_exp2f(sacc[ct][3] - m_run);
            ps += (p0 + p1) + (p2 + p3);
            uint2 wv;
            wv.x = pk2(p0, p1);
            wv.y = pk2(p2, p3);
            *(uint2*)&pwr[ct * 16 + lg * 4] = wv;
        }
        l_run += ps;
        // PV: O^T[d][q] += VT-tile . P-tile
        short8 pb0 = *(short8*)&pwr[lg * 8];
        short8 pb1 = *(short8*)&pwr[32 + lg * 8];
        __builtin_amdgcn_s_setprio(1);
#pragma unroll
        for (int m = 0; m < 4; ++m) {
            int r = m * 16 + lr, rs = r * 64, rx = r & 7;
            short8 v0 = *(short8*)&VTt[rs + (((0 + lg) ^ rx) << 3)];
            short8 v1 = *(short8*)&VTt[rs + (((4 + lg) ^ rx) << 3)];
            O[m] = MFMA16(v0, pb0, O[m]);
            O[m] = MFMA16(v1, pb1, O[m]);
        }
        __builtin_amdgcn_s_setprio(0);
        __syncthreads();  // all waves done reading tile before next stage
    }

    l_run += __shfl_xor(l_run, 16);
    l_run += __shfl_xor(l_run, 32);
    float inv = 1.f / l_run;
    int b = bh / 12, h = bh - b * 12;
    int q = r0 + w * 16 + lr;
    float* ob = out + (size_t)(b * 1024 + q) * 768 + h * 64;
#pragma unroll
    for (int m = 0; m < 4; ++m) {
        float4 o4;
        o4.x = O[m][0] * inv; o4.y = O[m][1] * inv;
        o4.z = O[m][2] * inv; o4.w = O[m][3] * inv;
        *(float4*)(ob + m * 16 + lg * 4) = o4;
    }
}

extern "C" void kernel_launch(void* const* d_in, const int* in_sizes, int n_in,
                              void* d_out, int out_size, void* d_ws, size_t ws_size,
                              hipStream_t stream) {
    const float* x  = (const float*)d_in[0];
    const float* W  = (const float*)d_in[1];
    const float* qb = (const float*)d_in[2];
    const float* lg = (const float*)d_in[3];
    const float* lb = (const float*)d_in[4];
    float* out = (float*)d_out;
    char* ws = (char*)d_ws;
    // Workspace layout (peak 28,704,768 bytes):
    short* xnb = (short*)(ws + 0);         // [4096][768] bf16 (dead after gemm)
    short* Wb  = (short*)(ws + 6291456);   // [2304][768] bf16
    short* Qb  = (short*)(ws + 9830400);   // [48][1024][64] bf16, pre-scaled by cq*log2e
    short* Kb  = (short*)(ws + 16121856);  // [48][1024][64] bf16
    short* VT  = (short*)(ws + 22413312);  // [48][64][1024] bf16
    short* KK  = (short*)(ws + 0);         // [48][1024][64] bf16, overlays dead xnb

    hipLaunchKernelGGL(prep_kernel, dim3(2752), dim3(256), 0, stream, x, lg, lb, W, xnb, Wb);
    hipLaunchKernelGGL(qkv_gemm, dim3(64, 18), dim3(256), 0, stream, xnb, Wb, qb, Qb, Kb, VT);
    hipLaunchKernelGGL(kk_kernel, dim3(32, 48), dim3(256), 0, stream, Kb, KK);
    hipLaunchKernelGGL(attn_kernel, dim3(768), dim3(256), 0, stream, Qb, Kb, KK, VT, out);
}